// Round 9
// baseline (700.648 us; speedup 1.0000x reference)
//
#include <hip/hip_runtime.h>

// MultiHeadAttention: B=2, S=2048, D=1024, H=16, HD=64, scores MULTIPLIED by 64.
// Round 8 (resubmit after GPU acquisition timeout): convert_w (tiny) -> projQK
// (fp32-A-in-LDS split-fp16 3-term, 64x128 tile, grid (64,8,2), XOR-swizzled
// global_load_lds staging) -> projV (three=0) -> transpose_v -> flash
// (XCD-pinned, split-K x3, fp16 partials) -> merge3.
// Workspace 65.5 MiB: 0 qh_hi | 8 qh_lo | 16 kh_hi | 24 kh_lo | 32 vhT
//   | 40 vh (dead after transpose) | 48 Wbase 12 MiB (dead after projV)
//   | Op fp16 3x8 MiB @40..64 (aliases vh+Wbase) | 64 ml 1.5 MiB

typedef _Float16 half4 __attribute__((ext_vector_type(4)));
typedef _Float16 half8 __attribute__((ext_vector_type(8)));
typedef float floatx4 __attribute__((ext_vector_type(4)));

#define MFMA_F16(a, b, c) __builtin_amdgcn_mfma_f32_16x16x32_f16((a), (b), (c), 0, 0, 0)

constexpr int SEQ = 2048;
constexpr int DM = 1024;
constexpr int NH = 16;
constexpr int HD = 64;
// 64 * log2(e): fold score scale + base-2 conversion into Q projection
constexpr float QSCALE = 92.33248261689366f;

// async 16B/lane global->LDS copy; LDS dest = wave-uniform base + lane*16
__device__ __forceinline__ void gl2lds16(const void* g, void* l) {
  __builtin_amdgcn_global_load_lds(
      (const __attribute__((address_space(1))) void*)g,
      (__attribute__((address_space(3))) void*)l, 16, 0, 0);
}

__device__ inline void split4(const float4 f, half4& h, half4& l) {
  h[0] = (_Float16)f.x; l[0] = (_Float16)(f.x - (float)h[0]);
  h[1] = (_Float16)f.y; l[1] = (_Float16)(f.y - (float)h[1]);
  h[2] = (_Float16)f.z; l[2] = (_Float16)(f.z - (float)h[2]);
  h[3] = (_Float16)f.w; l[3] = (_Float16)(f.w - (float)h[3]);
}

// ---------------- convert weights: fp32 -> fp16 hi (+lo for z<2) ------------
// grid 3072: z = blk>>10. Per z: 2M halfs = [hi 1M][lo 1M]
__global__ __launch_bounds__(256) void convert_w(
    const float* __restrict__ Wq, const float* __restrict__ Wk,
    const float* __restrict__ Wv, _Float16* __restrict__ Wbase)
{
  const int z = blockIdx.x >> 10;
  const int idx = (blockIdx.x & 1023) * 256 + threadIdx.x;   // float4 index
  const float* __restrict__ src = (z == 0) ? Wq : (z == 1) ? Wk : Wv;
  float4 f = ((const float4*)src)[idx];
  half4 h, l; split4(f, h, l);
  _Float16* Wh = Wbase + (size_t)z * 2097152;
  *(half4*)(Wh + (size_t)idx * 4) = h;
  if (z < 2) *(half4*)(Wh + 1048576 + (size_t)idx * 4) = l;
}

// ---------------- projection GEMM: y = x @ W^T ----------------
// 64(M)x128(N) tile, BK=64. A staged as RAW fp32 (XOR-16 image), split to
// hi/lo at fragment read. B pre-converted fp16 hi/lo (XOR-8 image).
// THREE=1: 3-term split-fp16 (Q,K via blockIdx.z); THREE=0: single-term (V).
template<int THREE>
__global__ __launch_bounds__(256, 3) void proj_kernel(
    const float* __restrict__ x0, const float* __restrict__ x1,
    const _Float16* __restrict__ Wb,
    _Float16* __restrict__ yh0, _Float16* __restrict__ yl0,
    _Float16* __restrict__ yh1, _Float16* __restrict__ yl1,
    float sc0, float sc1)
{
  __shared__ __align__(16) float    Af[64][64];                  // 16 KB
  __shared__ __align__(16) _Float16 Bhs[128][64];                // 16 KB
  __shared__ __align__(16) _Float16 Bls[THREE ? 128 : 1][64];    // 16 KB / 128 B

  const int z = blockIdx.z;
  const float* __restrict__ x = z ? x1 : x0;
  const _Float16* __restrict__ Whg = Wb + (size_t)z * 2097152;
  const _Float16* __restrict__ Wlg = Whg + 1048576;

  const int tid = threadIdx.x;
  const int bm = blockIdx.x;          // 0..63  (M=4096/64)
  const int bn = blockIdx.y;          // 0..7   (N=1024/128)
  const int lane = tid & 63, l15 = lane & 15, quad = lane >> 4;
  const int w = tid >> 6, wm = w >> 1, wn = w & 1;   // wave tile 32x64

  // staging lane geometry
  const int r4 = lane >> 4, pc16 = lane & 15;    // fp32 A: 4 rows/group, 16 chunks
  const int r8 = lane >> 3, pc8 = lane & 7;      // fp16 B: 8 rows/group, 8 chunks

  floatx4 acc[2][4];
  #pragma unroll
  for (int mt = 0; mt < 2; mt++)
    #pragma unroll
    for (int nt = 0; nt < 4; nt++)
      acc[mt][nt] = (floatx4){0.f, 0.f, 0.f, 0.f};

  for (int kk = 0; kk < DM; kk += 64) {
    __syncthreads();                             // prior tile reads complete
    #pragma unroll
    for (int i = 0; i < 4; i++) {
      const int g = w * 4 + i;                   // 0..15
      {
        const int row = g * 4 + r4;              // 0..63
        const int lc = pc16 ^ (row & 15);
        gl2lds16(x + (size_t)(bm * 64 + row) * DM + kk + lc * 4,
                 &Af[0][0] + g * 256);
      }
      {
        const int row = g * 8 + r8;              // 0..127
        const int lc = pc8 ^ (r8 & 7);
        gl2lds16(Whg + (size_t)(bn * 128 + row) * DM + kk + lc * 8,
                 &Bhs[0][0] + g * 512);
        if (THREE)
          gl2lds16(Wlg + (size_t)(bn * 128 + row) * DM + kk + lc * 8,
                   &Bls[0][0] + g * 512);
      }
    }
    __syncthreads();                             // staged tile visible

    #pragma unroll
    for (int kc = 0; kc < 2; kc++) {
      // A fragments: read fp32, split hi/lo in registers
      half8 ah[2], al[2];
      #pragma unroll
      for (int mt = 0; mt < 2; mt++) {
        const float* rp = &Af[wm * 32 + mt * 16 + l15][0];
        float4 f0 = *(const float4*)(rp + ((kc * 8 + quad * 2) ^ l15) * 4);
        float4 f1 = *(const float4*)(rp + ((kc * 8 + quad * 2 + 1) ^ l15) * 4);
        half4 h0, l0, h1, l1;
        split4(f0, h0, l0);
        split4(f1, h1, l1);
        #pragma unroll
        for (int j = 0; j < 4; j++) {
          ah[mt][j] = h0[j]; ah[mt][j + 4] = h1[j];
          al[mt][j] = l0[j]; al[mt][j + 4] = l1[j];
        }
      }
      // B fragments
      half8 bh_[4], bl[4];
      #pragma unroll
      for (int nt = 0; nt < 4; nt++) {
        const int row = wn * 64 + nt * 16 + l15;
        const int swz = ((kc * 4 + quad) ^ (l15 & 7)) * 8;
        bh_[nt] = *(const half8*)&Bhs[row][swz];
        if (THREE) bl[nt] = *(const half8*)&Bls[row][swz];
      }
      #pragma unroll
      for (int mt = 0; mt < 2; mt++)
        #pragma unroll
        for (int nt = 0; nt < 4; nt++) {
          if (THREE) {
            floatx4 t0 = MFMA_F16(ah[mt], bh_[nt], acc[mt][nt]);
            t0 = MFMA_F16(ah[mt], bl[nt], t0);
            acc[mt][nt] = MFMA_F16(al[mt], bh_[nt], t0);
          } else {
            acc[mt][nt] = MFMA_F16(ah[mt], bh_[nt], acc[mt][nt]);
          }
        }
    }
  }

  const float scale = z ? sc1 : sc0;
  _Float16* yh = z ? yh1 : yh0;
  _Float16* yl = z ? yl1 : yl0;
  #pragma unroll
  for (int mt = 0; mt < 2; mt++)
    #pragma unroll
    for (int nt = 0; nt < 4; nt++)
      #pragma unroll
      for (int r = 0; r < 4; r++) {
        int gm = bm * 64 + wm * 32 + mt * 16 + quad * 4 + r;    // (b,s)
        int gn = bn * 128 + wn * 64 + nt * 16 + l15;            // h*64+d
        int b = gm >> 11, s = gm & 2047;
        int h = gn >> 6, d = gn & 63;
        size_t idx = ((size_t)(b * NH + h) * SEQ + s) * HD + d;
        float val = acc[mt][nt][r] * scale;
        _Float16 hi = (_Float16)val;
        yh[idx] = hi;
        if (THREE) yl[idx] = (_Float16)(val - (float)hi);
      }
}

// ---------------- vh [b,h,s,64] -> vhT [b,h,64,perm(s)] ----------------
// perm within 32-group: s = 32c+16a+4q+b -> pos = 32c+8q+4a+b, so flash PV
// A-fragments (key order 32kc+16(j>>2)+4quad+(j&3)) are contiguous b128 reads.
__global__ __launch_bounds__(256) void transpose_v(const _Float16* __restrict__ vh,
                                                   _Float16* __restrict__ vhT)
{
  __shared__ __align__(16) _Float16 T[128][72];
  const int bh = blockIdx.x, sc = blockIdx.y, tid = threadIdx.x;
  const _Float16* src = vh + ((size_t)bh * SEQ + sc * 128) * HD;
  #pragma unroll
  for (int i = 0; i < 4; i++) {
    int c = i * 256 + tid, row = c >> 3, off = (c & 7) * 8;
    *(half8*)&T[row][off] = *(const half8*)(src + (size_t)row * HD + off);
  }
  __syncthreads();
  _Float16* dst = vhT + (size_t)bh * HD * SEQ + sc * 128;
  #pragma unroll
  for (int i = 0; i < 4; i++) {
    int c = i * 256 + tid, hd = c >> 4, off = (c & 15) * 8;
    int base32 = off & ~31, qsel = (off >> 3) & 3;
    half8 vv;
    #pragma unroll
    for (int j = 0; j < 8; j++) {
      int s_local = base32 + 16 * (j >> 2) + 4 * qsel + (j & 3);
      vv[j] = T[s_local][hd];
    }
    *(half8*)(dst + (size_t)hd * SEQ + off) = vv;
  }
}

// ---------------- flash attention v8: XCD pin + split-K x3 ------------------
// grid 1536; bh = (id&7)+8*((id>>3)&3); rem=(id>>5): qb=rem&15, split=rem>>4.
// splits cover kt [0,11),[11,22),[22,32). fp16 unnormalized partials + (m,l).
__global__ __launch_bounds__(256, 6) void flash_kernel(
    const _Float16* __restrict__ qh_hi, const _Float16* __restrict__ qh_lo,
    const _Float16* __restrict__ kh_hi, const _Float16* __restrict__ kh_lo,
    const _Float16* __restrict__ vhT, _Float16* __restrict__ Op,
    float2* __restrict__ ml)
{
  __shared__ __align__(16) _Float16 Kh[64][64];
  __shared__ __align__(16) _Float16 Kl[64][64];
  __shared__ __align__(16) _Float16 Vt[64][64];   // [d][permuted key]

  const int id = blockIdx.x;
  const int seq_ = id >> 3;
  const int bh = (id & 7) + 8 * (seq_ & 3);       // 0..31, pinned to XCD id&7
  const int rem = seq_ >> 2;                      // 0..47
  const int qb = rem & 15;                        // 0..15
  const int split = rem >> 4;                     // 0..2
  const int tid = threadIdx.x;
  const int wq = tid >> 6;
  const int lane = tid & 63, l15 = lane & 15, quad = lane >> 4;

  const size_t bh_off = (size_t)bh * SEQ * HD;
  const _Float16* __restrict__ kh_p = kh_hi + bh_off;
  const _Float16* __restrict__ kl_p = kh_lo + bh_off;
  const _Float16* __restrict__ vt_p = vhT + (size_t)bh * HD * SEQ;
  const int qrow0 = qb * 128 + wq * 32;

  // Q as B-operand fragments: lane holds n=q=l15, k=d=kc*32+quad*8+j
  half8 bqh[2][2], bql[2][2];         // [g][kc]
  #pragma unroll
  for (int g = 0; g < 2; g++) {
    const _Float16* qp_h = qh_hi + bh_off + (size_t)(qrow0 + g * 16 + l15) * HD;
    const _Float16* qp_l = qh_lo + bh_off + (size_t)(qrow0 + g * 16 + l15) * HD;
    #pragma unroll
    for (int kc = 0; kc < 2; kc++) {
      bqh[g][kc] = *(const half8*)(qp_h + kc * 32 + quad * 8);
      bql[g][kc] = *(const half8*)(qp_l + kc * 32 + quad * 8);
    }
  }

  // staging: wave wq covers groups 2wq, 2wq+1 per array (8 rows x 1 KiB each)
  const int r8 = lane >> 3;
  const int cp8 = ((lane & 7) ^ r8) * 8;

  float m_[2] = {-3.0e38f, -3.0e38f};
  float l_[2] = {0.f, 0.f};
  floatx4 Oacc[2][4];
  #pragma unroll
  for (int g = 0; g < 2; g++)
    #pragma unroll
    for (int nd = 0; nd < 4; nd++) Oacc[g][nd] = (floatx4){0.f, 0.f, 0.f, 0.f};

  const int kt_begin = split * 11;
  const int kt_end = (split == 2) ? 32 : (kt_begin + 11);
  for (int kt = kt_begin; kt < kt_end; kt++) {
    const int kbase = kt * 64;
    __syncthreads();
    #pragma unroll
    for (int i = 0; i < 2; i++) {
      const int g = wq * 2 + i;
      const int r = g * 8 + r8;
      gl2lds16(kh_p + (size_t)(kbase + r) * HD + cp8, &Kh[0][0] + g * 512);
      gl2lds16(kl_p + (size_t)(kbase + r) * HD + cp8, &Kl[0][0] + g * 512);
      gl2lds16(vt_p + (size_t)r * SEQ + kbase + cp8, &Vt[0][0] + g * 512);
    }
    __syncthreads();

    // S^T = K·Q^T (3-term split fp16), both q-groups share K fragments
    floatx4 sacc[2][4];
    #pragma unroll
    for (int nt = 0; nt < 4; nt++) {
      const int r7 = l15 & 7;
      half8 akh0 = *(const half8*)&Kh[nt * 16 + l15][((0 * 4 + quad) ^ r7) * 8];
      half8 akh1 = *(const half8*)&Kh[nt * 16 + l15][((1 * 4 + quad) ^ r7) * 8];
      half8 akl0 = *(const half8*)&Kl[nt * 16 + l15][((0 * 4 + quad) ^ r7) * 8];
      half8 akl1 = *(const half8*)&Kl[nt * 16 + l15][((1 * 4 + quad) ^ r7) * 8];
      #pragma unroll
      for (int g = 0; g < 2; g++) {
        floatx4 s4 = (floatx4){0.f, 0.f, 0.f, 0.f};
        s4 = MFMA_F16(akh0, bqh[g][0], s4);
        s4 = MFMA_F16(akh1, bqh[g][1], s4);
        s4 = MFMA_F16(akh0, bql[g][0], s4);
        s4 = MFMA_F16(akh1, bql[g][1], s4);
        s4 = MFMA_F16(akl0, bqh[g][0], s4);
        s4 = MFMA_F16(akl1, bqh[g][1], s4);
        sacc[g][nt] = s4;
      }
    }

    // V A-fragments (permuted image), shared by both q-groups
    half8 av[4][2];
    {
      const int r7 = l15 & 7;
      #pragma unroll
      for (int nd = 0; nd < 4; nd++) {
        av[nd][0] = *(const half8*)&Vt[nd * 16 + l15][((0 * 4 + quad) ^ r7) * 8];
        av[nd][1] = *(const half8*)&Vt[nd * 16 + l15][((1 * 4 + quad) ^ r7) * 8];
      }
    }

    #pragma unroll
    for (int g = 0; g < 2; g++) {
      // online softmax over 64 keys: in-lane + 2 cross-quad shuffles
      float rmax = sacc[g][0][0];
      #pragma unroll
      for (int nt = 0; nt < 4; nt++)
        #pragma unroll
        for (int r = 0; r < 4; r++) rmax = fmaxf(rmax, sacc[g][nt][r]);
      rmax = fmaxf(rmax, __shfl_xor(rmax, 16, 64));
      rmax = fmaxf(rmax, __shfl_xor(rmax, 32, 64));
      const float mnew = fmaxf(m_[g], rmax);
      const float alpha = exp2f(m_[g] - mnew);
      m_[g] = mnew;

      float rsum = 0.f;
      #pragma unroll
      for (int nt = 0; nt < 4; nt++)
        #pragma unroll
        for (int r = 0; r < 4; r++) {
          float p = exp2f(sacc[g][nt][r] - mnew);
          sacc[g][nt][r] = p;
          rsum += p;
        }
      rsum += __shfl_xor(rsum, 16, 64);
      rsum += __shfl_xor(rsum, 32, 64);
      l_[g] = l_[g] * alpha + rsum;

      // P pack for PV B-operand: bp8[kc][j] = p[2kc + (j>>2)][j&3] (in-lane)
      half8 bp8[2];
      #pragma unroll
      for (int kc = 0; kc < 2; kc++)
        #pragma unroll
        for (int j = 0; j < 8; j++)
          bp8[kc][j] = (_Float16)sacc[g][2 * kc + (j >> 2)][j & 3];

      #pragma unroll
      for (int nd = 0; nd < 4; nd++) {
        Oacc[g][nd][0] *= alpha; Oacc[g][nd][1] *= alpha;
        Oacc[g][nd][2] *= alpha; Oacc[g][nd][3] *= alpha;
        Oacc[g][nd] = MFMA_F16(av[nd][0], bp8[0], Oacc[g][nd]);
        Oacc[g][nd] = MFMA_F16(av[nd][1], bp8[1], Oacc[g][nd]);
      }
    }
  }

  // epilogue: unnormalized O^T partial (fp16) + (m,l)
  const size_t fqbase = (size_t)bh * SEQ + qrow0;
  #pragma unroll
  for (int g = 0; g < 2; g++) {
    const size_t fq = fqbase + g * 16 + l15;
    _Float16* ob = Op + ((size_t)split * 65536 + fq) * HD;
    #pragma unroll
    for (int nd = 0; nd < 4; nd++) {
      half4 hv;
      hv[0] = (_Float16)Oacc[g][nd][0];
      hv[1] = (_Float16)Oacc[g][nd][1];
      hv[2] = (_Float16)Oacc[g][nd][2];
      hv[3] = (_Float16)Oacc[g][nd][3];
      *(half4*)(ob + nd * 16 + quad * 4) = hv;
    }
    if (quad == 0) ml[(size_t)split * 65536 + fq] = make_float2(m_[g], l_[g]);
  }
}

// ---------------- merge the three split-K partials ----------------
__global__ __launch_bounds__(256) void merge_kernel(const _Float16* __restrict__ Op,
                                                    const float2* __restrict__ ml,
                                                    float* __restrict__ out)
{
  const int tid = threadIdx.x;
  const int fq = blockIdx.x * 64 + (tid >> 2);
  const int dp = (tid & 3) * 16;
  float2 ma = ml[fq], mb = ml[65536 + fq], mc = ml[131072 + fq];
  float M = fmaxf(ma.x, fmaxf(mb.x, mc.x));
  float wa = exp2f(ma.x - M), wb = exp2f(mb.x - M), wc = exp2f(mc.x - M);
  float rinv = 1.0f / (ma.y * wa + mb.y * wb + mc.y * wc);
  int bh = fq >> 11, s = fq & 2047, b = bh >> 4, h = bh & 15;
  float* ob = out + ((size_t)(b * SEQ + s)) * DM + h * HD + dp;
  const _Float16* pa = Op + (size_t)fq * HD + dp;
  const _Float16* pb = pa + (size_t)65536 * HD;
  const _Float16* pc = pb + (size_t)65536 * HD;
  #pragma unroll
  for (int j = 0; j < 4; j++) {
    half4 a = *(const half4*)(pa + 4 * j);
    half4 c = *(const half4*)(pb + 4 * j);
    half4 d = *(const half4*)(pc + 4 * j);
    float4 r;
    r.x = ((float)a[0] * wa + (float)c[0] * wb + (float)d[0] * wc) * rinv;
    r.y = ((float)a[1] * wa + (float)c[1] * wb + (float)d[1] * wc) * rinv;
    r.z = ((float)a[2] * wa + (float)c[2] * wb + (float)d[2] * wc) * rinv;
    r.w = ((float)a[3] * wa + (float)c[3] * wb + (float)d[3] * wc) * rinv;
    *(float4*)(ob + 4 * j) = r;
  }
}

extern "C" void kernel_launch(void* const* d_in, const int* in_sizes, int n_in,
                              void* d_out, int out_size, void* d_ws, size_t ws_size,
                              hipStream_t stream) {
  const float* q  = (const float*)d_in[0];
  const float* k  = (const float*)d_in[1];
  const float* v  = (const float*)d_in[2];
  const float* Wq = (const float*)d_in[3];
  const float* Wk = (const float*)d_in[4];
  const float* Wv = (const float*)d_in[5];
  float* out = (float*)d_out;

  char* W = (char*)d_ws;
  const size_t MiB = 1ull << 20;
  _Float16* qh_hi = (_Float16*)(W + 0 * MiB);
  _Float16* qh_lo = (_Float16*)(W + 8 * MiB);
  _Float16* kh_hi = (_Float16*)(W + 16 * MiB);
  _Float16* kh_lo = (_Float16*)(W + 24 * MiB);
  _Float16* vhT   = (_Float16*)(W + 32 * MiB);
  _Float16* vh    = (_Float16*)(W + 40 * MiB);  // dead after transpose_v
  _Float16* Wbase = (_Float16*)(W + 48 * MiB);  // 12 MiB; dead after projV
  _Float16* Oph   = (_Float16*)(W + 40 * MiB);  // 3 x 8 MiB, aliases vh/Wbase
  float2*   mlp   = (float2*)  (W + 64 * MiB);  // 1.5 MiB; total 65.5 MiB

  convert_w<<<3072, 256, 0, stream>>>(Wq, Wk, Wv, Wbase);
  proj_kernel<1><<<dim3(64, 8, 2), 256, 0, stream>>>(
      q, k, Wbase, qh_hi, qh_lo, kh_hi, kh_lo, QSCALE, 1.0f);
  proj_kernel<0><<<dim3(64, 8, 1), 256, 0, stream>>>(
      v, v, Wbase + (size_t)2 * 2097152, vh, vh, vh, vh, 1.0f, 1.0f);
  transpose_v<<<dim3(32, 16), 256, 0, stream>>>(vh, vhT);
  flash_kernel<<<1536, 256, 0, stream>>>(qh_hi, qh_lo, kh_hi, kh_lo, vhT, Oph, mlp);
  merge_kernel<<<1024, 256, 0, stream>>>(Oph, mlp, out);
}